// Round 3
// baseline (917.344 us; speedup 1.0000x reference)
//
#include <hip/hip_runtime.h>
#include <hip/hip_bf16.h>
#include <math.h>

constexpr int IN_C = 1024;
constexpr int HEADS = 4;
constexpr int F1 = 256;
constexpr int OUT_C = 64;
constexpr float NEG = 0.2f;

using bf16x8 = __attribute__((ext_vector_type(8))) short;
using f32x4 = __attribute__((ext_vector_type(4))) float;

__device__ __forceinline__ float leaky(float x) { return x > 0.f ? x : NEG * x; }

__device__ __forceinline__ unsigned short bf16bits(float v) {
  __hip_bfloat16 b = __float2bfloat16(v);
  return *reinterpret_cast<unsigned short*>(&b);
}

#define GLD_LDS16(g, l)                                                        \
  __builtin_amdgcn_global_load_lds(                                            \
      (const __attribute__((address_space(1))) void*)(g),                      \
      (__attribute__((address_space(3))) void*)(l), 16, 0, 0)

// ---------------- f32 -> bf16 convert (for W1) ----------------
__global__ void cvt_bf16_kernel(const float* __restrict__ in,
                                unsigned short* __restrict__ out, int n) {
  int i = blockIdx.x * blockDim.x + threadIdx.x;
  if (i < n) out[i] = bf16bits(in[i]);
}

// ---------------- GEMM1: H[M,256] = X[M,1024] * W1[256,1024]^T, bf16 MFMA ----------
// BM=64, BN=256 (full N: x read exactly once), BK=64. 4 waves; wave w = head w.
// B: global_load_lds (16B) with xor-swizzled global cols -> conflict-free ds_read.
// A: manual f32 load + v_cvt_pk_bf16 + padded-stride LDS tile.
constexpr int LDTA = 72;  // ushort stride for As (64 + 8 pad)

__global__ __launch_bounds__(256, 2) void gemm1_mfma(const float* __restrict__ X,
                                                     const unsigned short* __restrict__ Wb,
                                                     float* __restrict__ H, int M) {
  __shared__ unsigned short As[64 * LDTA];   // 9216 B
  __shared__ unsigned short Bs[256 * 64];    // 32768 B, linear (glds requirement)
  const int tid = threadIdx.x;
  const int wave = tid >> 6;
  const int lane = tid & 63;
  const int m15 = lane & 15;
  const int q = lane >> 4;
  const int bm = blockIdx.x * 64;

  f32x4 acc[4][4];
#pragma unroll
  for (int i = 0; i < 4; ++i)
#pragma unroll
    for (int j = 0; j < 4; ++j) acc[i][j] = (f32x4){0.f, 0.f, 0.f, 0.f};

  // A staging mapping: 4 lanes per row (good coalescing), 16 f32 per thread
  const int ar = tid >> 2;         // 0..63 row within tile
  const int acg = (tid & 3) * 16;  // f32 col offset
  const int agr = (bm + ar < M) ? (bm + ar) : (M - 1);
  const float* aptr = X + (size_t)agr * IN_C + acg;

  for (int kt = 0; kt < IN_C; kt += 64) {
    // ---- B staging: 8 passes x 1KB per wave, xor-swizzled source cols ----
#pragma unroll
    for (int p = 0; p < 8; ++p) {
      int s = p * 256 + tid;          // 16B slot index
      int r = s >> 3;                 // B row (0..255)
      int cb = s & 7;                 // col-block within row
      const unsigned short* g = Wb + (size_t)r * IN_C + kt + ((cb ^ (r & 7)) << 3);
      GLD_LDS16(g, &Bs[(p * 256 + wave * 64) * 8]);
    }
    // ---- A staging: 4 float4 loads -> 16 bf16 -> 2 x ds_write_b128 ----
    float4 a0 = *(const float4*)(aptr + kt + 0);
    float4 a1 = *(const float4*)(aptr + kt + 4);
    float4 a2 = *(const float4*)(aptr + kt + 8);
    float4 a3 = *(const float4*)(aptr + kt + 12);
    union { uint4 u4[2]; __hip_bfloat162 h[8]; } pk;
    pk.h[0] = __float22bfloat162_rn(make_float2(a0.x, a0.y));
    pk.h[1] = __float22bfloat162_rn(make_float2(a0.z, a0.w));
    pk.h[2] = __float22bfloat162_rn(make_float2(a1.x, a1.y));
    pk.h[3] = __float22bfloat162_rn(make_float2(a1.z, a1.w));
    pk.h[4] = __float22bfloat162_rn(make_float2(a2.x, a2.y));
    pk.h[5] = __float22bfloat162_rn(make_float2(a2.z, a2.w));
    pk.h[6] = __float22bfloat162_rn(make_float2(a3.x, a3.y));
    pk.h[7] = __float22bfloat162_rn(make_float2(a3.z, a3.w));
    *(uint4*)&As[ar * LDTA + acg] = pk.u4[0];
    *(uint4*)&As[ar * LDTA + acg + 8] = pk.u4[1];
    __syncthreads();

#pragma unroll
    for (int k0 = 0; k0 < 64; k0 += 32) {
      bf16x8 af[4], bfr[4];
#pragma unroll
      for (int i = 0; i < 4; ++i)
        af[i] = *(const bf16x8*)&As[(i * 16 + m15) * LDTA + k0 + q * 8];
#pragma unroll
      for (int j = 0; j < 4; ++j) {
        int rb = wave * 64 + j * 16 + m15;
        int cbp = ((k0 >> 3) + q) ^ (rb & 7);
        bfr[j] = *(const bf16x8*)&Bs[rb * 64 + cbp * 8];
      }
#pragma unroll
      for (int i = 0; i < 4; ++i)
#pragma unroll
        for (int j = 0; j < 4; ++j)
          acc[i][j] = __builtin_amdgcn_mfma_f32_16x16x32_bf16(af[i], bfr[j], acc[i][j], 0, 0, 0);
    }
    __syncthreads();
  }
  // epilogue: D row = q*4 + r (+ i*16), col = m15 (+ j*16 + wave*64)
#pragma unroll
  for (int i = 0; i < 4; ++i) {
#pragma unroll
    for (int r = 0; r < 4; ++r) {
      int row = bm + i * 16 + q * 4 + r;
      if (row < M) {
#pragma unroll
        for (int j = 0; j < 4; ++j)
          H[(size_t)row * F1 + wave * 64 + j * 16 + m15] = acc[i][j][r];
      }
    }
  }
}

// ---------------- GEMM (f32 VALU): C[M,N] = A[M,K] * B[N,K]^T  (layer 2) -----------
__global__ __launch_bounds__(256) void gemm_nt(const float* __restrict__ A,
                                               const float* __restrict__ B,
                                               float* __restrict__ C,
                                               int M, int N, int K) {
  __shared__ float As[32][68];
  __shared__ float Bs[32][68];
  const int bm = blockIdx.x * 64;
  const int bn = blockIdx.y * 64;
  const int tid = threadIdx.x;
  const int tx = tid & 15;
  const int ty = tid >> 4;
  float acc[4][4] = {{0.f, 0.f, 0.f, 0.f}};
  const int lr = tid >> 3;
  const int lc = (tid & 7) << 2;
  for (int kt = 0; kt < K; kt += 32) {
#pragma unroll
    for (int p = 0; p < 2; ++p) {
      int r = lr + p * 32;
      int gr = bm + r;
      float4 va = make_float4(0.f, 0.f, 0.f, 0.f);
      if (gr < M) va = *(const float4*)(A + (size_t)gr * K + kt + lc);
      As[lc + 0][r] = va.x; As[lc + 1][r] = va.y;
      As[lc + 2][r] = va.z; As[lc + 3][r] = va.w;
      int gn = bn + r;
      float4 vb = make_float4(0.f, 0.f, 0.f, 0.f);
      if (gn < N) vb = *(const float4*)(B + (size_t)gn * K + kt + lc);
      Bs[lc + 0][r] = vb.x; Bs[lc + 1][r] = vb.y;
      Bs[lc + 2][r] = vb.z; Bs[lc + 3][r] = vb.w;
    }
    __syncthreads();
#pragma unroll
    for (int k = 0; k < 32; ++k) {
      float4 a = *(const float4*)&As[k][ty * 4];
      float4 b = *(const float4*)&Bs[k][tx * 4];
      float av[4] = {a.x, a.y, a.z, a.w};
      float bv[4] = {b.x, b.y, b.z, b.w};
#pragma unroll
      for (int i = 0; i < 4; ++i)
#pragma unroll
        for (int j = 0; j < 4; ++j) acc[i][j] = fmaf(av[i], bv[j], acc[i][j]);
    }
    __syncthreads();
  }
#pragma unroll
  for (int i = 0; i < 4; ++i) {
    int row = bm + ty * 4 + i;
    if (row < M) {
#pragma unroll
      for (int j = 0; j < 4; ++j)
        C[(size_t)row * N + bn + tx * 4 + j] = acc[i][j];
    }
  }
}

// ---------------- CSR build ----------------
__global__ void degree_kernel(const int* __restrict__ ei, int E, int N,
                              int* __restrict__ deg) {
  int e = blockIdx.x * blockDim.x + threadIdx.x;
  if (e >= E + N) return;
  int dst = (e < E) ? ei[E + e] : (e - E);
  atomicAdd(&deg[dst], 1);
}

__global__ __launch_bounds__(256) void scan_block_sums(const int* __restrict__ deg,
                                                       int* __restrict__ part, int n) {
  __shared__ int sm[256];
  int t = threadIdx.x;
  int i = blockIdx.x * 256 + t;
  sm[t] = (i < n) ? deg[i] : 0;
  __syncthreads();
  for (int off = 128; off > 0; off >>= 1) {
    if (t < off) sm[t] += sm[t + off];
    __syncthreads();
  }
  if (t == 0) part[blockIdx.x] = sm[0];
}

__global__ __launch_bounds__(256) void scan_partials(int* __restrict__ part, int P) {
  __shared__ int sm[256];
  int t = threadIdx.x;
  int v = (t < P) ? part[t] : 0;
  sm[t] = v;
  __syncthreads();
  for (int off = 1; off < 256; off <<= 1) {
    int u = (t >= off) ? sm[t - off] : 0;
    __syncthreads();
    sm[t] += u;
    __syncthreads();
  }
  if (t < P) part[t] = sm[t];  // inclusive
}

__global__ __launch_bounds__(256) void scan_final(const int* __restrict__ deg,
                                                  const int* __restrict__ part,
                                                  int* __restrict__ row_ptr, int n) {
  __shared__ int sm[256];
  int t = threadIdx.x;
  int i = blockIdx.x * 256 + t;
  sm[t] = (i < n) ? deg[i] : 0;
  __syncthreads();
  for (int off = 1; off < 256; off <<= 1) {
    int u = (t >= off) ? sm[t - off] : 0;
    __syncthreads();
    sm[t] += u;
    __syncthreads();
  }
  int base = blockIdx.x ? part[blockIdx.x - 1] : 0;
  if (i < n) row_ptr[i + 1] = base + sm[t];
  if (i == 0) row_ptr[0] = 0;
}

__global__ void scatter_kernel(const int* __restrict__ ei, int E, int N,
                               const int* __restrict__ row_ptr, int* __restrict__ fill,
                               int* __restrict__ col) {
  int e = blockIdx.x * blockDim.x + threadIdx.x;
  if (e >= E + N) return;
  int src, dst;
  if (e < E) { src = ei[e]; dst = ei[E + e]; }
  else       { src = e - E; dst = e - E; }
  int pos = row_ptr[dst] + atomicAdd(&fill[dst], 1);
  col[pos] = src;
}

// ---------------- alpha dot-products: one wave per node ----------------
template <int NH>
__global__ __launch_bounds__(256) void alpha_kernel(const float* __restrict__ h,
                                                    const float* __restrict__ a_src,
                                                    const float* __restrict__ a_dst,
                                                    float* __restrict__ as_out,
                                                    float* __restrict__ ad_out, int N) {
  int w = (blockIdx.x * blockDim.x + threadIdx.x) >> 6;
  int lane = threadIdx.x & 63;
  if (w >= N) return;
  float s[NH], d[NH];
#pragma unroll
  for (int hh = 0; hh < NH; ++hh) {
    float v = h[(size_t)w * (NH * 64) + hh * 64 + lane];
    s[hh] = v * a_src[hh * 64 + lane];
    d[hh] = v * a_dst[hh * 64 + lane];
  }
#pragma unroll
  for (int hh = 0; hh < NH; ++hh) {
    for (int off = 32; off > 0; off >>= 1) {
      s[hh] += __shfl_xor(s[hh], off, 64);
      d[hh] += __shfl_xor(d[hh], off, 64);
    }
  }
  if (lane == 0) {
#pragma unroll
    for (int hh = 0; hh < NH; ++hh) {
      as_out[w * NH + hh] = s[hh];
      ad_out[w * NH + hh] = d[hh];
    }
  }
}

// ------- softmax+aggregate: ONE WAVE PER (dst, head) — max TLP for the gather ------
template <int NH>
__global__ __launch_bounds__(256) void agg2(const float* __restrict__ h,
                                            const float* __restrict__ as,
                                            const float* __restrict__ ad,
                                            const int* __restrict__ row_ptr,
                                            const int* __restrict__ col,
                                            const float* __restrict__ bias,
                                            float* __restrict__ out, int N,
                                            int do_elu) {
  int gw = (blockIdx.x * blockDim.x + threadIdx.x) >> 6;
  int lane = threadIdx.x & 63;
  int dst = (NH == 4) ? (gw >> 2) : gw;
  int hh  = (NH == 4) ? (gw & 3) : 0;
  if (dst >= N) return;
  const int s0 = row_ptr[dst], s1 = row_ptr[dst + 1];
  const float adl = ad[dst * NH + hh];

  // pass 1: max over edges (lanes parallel over edges)
  float m = -1e30f;
  for (int i = s0 + lane; i < s1; i += 64)
    m = fmaxf(m, leaky(as[col[i] * NH + hh] + adl));
  for (int o = 32; o > 0; o >>= 1) m = fmaxf(m, __shfl_xor(m, o, 64));

  // pass 2: denom
  float den = 0.f;
  for (int i = s0 + lane; i < s1; i += 64)
    den += __expf(leaky(as[col[i] * NH + hh] + adl) - m);
  for (int o = 32; o > 0; o >>= 1) den += __shfl_xor(den, o, 64);
  const float inv = 1.f / den;

  // pass 3: lane = channel, serial over edges (as[] is L2-resident: 800 KB)
  float acc = 0.f;
  for (int i = s0; i < s1; ++i) {
    int s = col[i];
    float e = __expf(leaky(as[s * NH + hh] + adl) - m);
    acc = fmaf(e, h[(size_t)s * (NH * 64) + hh * 64 + lane], acc);
  }
  float v = acc * inv + bias[hh * 64 + lane];
  if (do_elu) v = v > 0.f ? v : (__expf(v) - 1.f);
  out[(size_t)dst * (NH * 64) + hh * 64 + lane] = v;
}

extern "C" void kernel_launch(void* const* d_in, const int* in_sizes, int n_in,
                              void* d_out, int out_size, void* d_ws, size_t ws_size,
                              hipStream_t stream) {
  const float* x      = (const float*)d_in[0];
  const int*   ei     = (const int*)d_in[1];
  const float* W1     = (const float*)d_in[2];
  const float* a_src1 = (const float*)d_in[3];
  const float* a_dst1 = (const float*)d_in[4];
  const float* b1     = (const float*)d_in[5];
  const float* W2     = (const float*)d_in[6];
  const float* a_src2 = (const float*)d_in[7];
  const float* a_dst2 = (const float*)d_in[8];
  const float* b2     = (const float*)d_in[9];
  float* out = (float*)d_out;

  const int N = in_sizes[0] / IN_C;
  const int E = in_sizes[1] / 2;
  const int ET = E + N;

  char* ws = (char*)d_ws;
  size_t off = 0;
  auto alloc = [&](size_t bytes) -> void* {
    void* p = ws + off;
    off = (off + bytes + 255) & ~(size_t)255;
    return p;
  };
  float* h1      = (float*)alloc((size_t)N * F1 * 4);
  float* y1      = (float*)alloc((size_t)N * F1 * 4);
  float* h2      = (float*)alloc((size_t)N * OUT_C * 4);
  float* as1     = (float*)alloc((size_t)N * HEADS * 4);
  float* ad1     = (float*)alloc((size_t)N * HEADS * 4);
  float* as2     = (float*)alloc((size_t)N * 4);
  float* ad2     = (float*)alloc((size_t)N * 4);
  int*   deg     = (int*)alloc((size_t)N * 4);
  int*   row_ptr = (int*)alloc((size_t)(N + 1) * 4);
  int*   fill    = (int*)alloc((size_t)N * 4);
  int*   col     = (int*)alloc((size_t)ET * 4);
  int*   part    = (int*)alloc(1024 * 4);
  unsigned short* W1b = (unsigned short*)alloc((size_t)F1 * IN_C * 2);
  (void)off; (void)ws_size; (void)n_in; (void)out_size;

  hipMemsetAsync(deg, 0, (size_t)N * 4, stream);
  hipMemsetAsync(fill, 0, (size_t)N * 4, stream);

  // W1 -> bf16
  cvt_bf16_kernel<<<(F1 * IN_C + 255) / 256, 256, 0, stream>>>(W1, W1b, F1 * IN_C);

  // CSR by destination (shared by both layers)
  const int P = (N + 255) / 256;
  degree_kernel<<<(ET + 255) / 256, 256, 0, stream>>>(ei, E, N, deg);
  scan_block_sums<<<P, 256, 0, stream>>>(deg, part, N);
  scan_partials<<<1, 256, 0, stream>>>(part, P);
  scan_final<<<P, 256, 0, stream>>>(deg, part, row_ptr, N);
  scatter_kernel<<<(ET + 255) / 256, 256, 0, stream>>>(ei, E, N, row_ptr, fill, col);

  // ---- layer 1 ----
  gemm1_mfma<<<(N + 63) / 64, 256, 0, stream>>>(x, W1b, h1, N);
  alpha_kernel<HEADS><<<((size_t)N * 64 + 255) / 256, 256, 0, stream>>>(h1, a_src1, a_dst1, as1, ad1, N);
  agg2<HEADS><<<((size_t)N * HEADS * 64 + 255) / 256, 256, 0, stream>>>(h1, as1, ad1, row_ptr, col, b1, y1, N, 1);

  // ---- layer 2 ----
  dim3 g2((N + 63) / 64, OUT_C / 64);
  gemm_nt<<<g2, 256, 0, stream>>>(y1, W2, h2, N, OUT_C, F1);
  alpha_kernel<1><<<((size_t)N * 64 + 255) / 256, 256, 0, stream>>>(h2, a_src2, a_dst2, as2, ad2, N);
  agg2<1><<<((size_t)N * 64 + 255) / 256, 256, 0, stream>>>(h2, as2, ad2, row_ptr, col, b2, out, N, 0);
}

// Round 4
// 624.683 us; speedup vs baseline: 1.4685x; 1.4685x over previous
//
#include <hip/hip_runtime.h>
#include <hip/hip_bf16.h>
#include <math.h>

constexpr int IN_C = 1024;
constexpr int HEADS = 4;
constexpr int F1 = 256;
constexpr int OUT_C = 64;
constexpr float NEG = 0.2f;

using bf16x8 = __attribute__((ext_vector_type(8))) short;
using f32x4 = __attribute__((ext_vector_type(4))) float;

__device__ __forceinline__ float leaky(float x) { return x > 0.f ? x : NEG * x; }

__device__ __forceinline__ unsigned short bf16bits(float v) {
  __hip_bfloat16 b = __float2bfloat16(v);
  return *reinterpret_cast<unsigned short*>(&b);
}
__device__ __forceinline__ float bf2f(unsigned short u) {
  unsigned v = (unsigned)u << 16;
  union { unsigned u; float f; } c; c.u = v; return c.f;
}

#define GLD_LDS16(g, l)                                                        \
  __builtin_amdgcn_global_load_lds(                                            \
      (const __attribute__((address_space(1))) void*)(g),                      \
      (__attribute__((address_space(3))) void*)(l), 16, 0, 0)

// ---------------- f32 -> bf16 convert (for W1) ----------------
__global__ void cvt_bf16_kernel(const float* __restrict__ in,
                                unsigned short* __restrict__ out, int n) {
  int i = blockIdx.x * blockDim.x + threadIdx.x;
  if (i < n) out[i] = bf16bits(in[i]);
}

// ---------------- GEMM1: H[M,256] = X * W1^T, bf16 MFMA; OUTPUT IS BF16 -----------
constexpr int LDTA = 72;  // ushort stride for As (64 + 8 pad)

__global__ __launch_bounds__(256, 2) void gemm1_mfma(const float* __restrict__ X,
                                                     const unsigned short* __restrict__ Wb,
                                                     unsigned short* __restrict__ Hb, int M) {
  __shared__ unsigned short As[64 * LDTA];
  __shared__ unsigned short Bs[256 * 64];
  const int tid = threadIdx.x;
  const int wave = tid >> 6;
  const int lane = tid & 63;
  const int m15 = lane & 15;
  const int q = lane >> 4;
  const int bm = blockIdx.x * 64;

  f32x4 acc[4][4];
#pragma unroll
  for (int i = 0; i < 4; ++i)
#pragma unroll
    for (int j = 0; j < 4; ++j) acc[i][j] = (f32x4){0.f, 0.f, 0.f, 0.f};

  const int ar = tid >> 2;
  const int acg = (tid & 3) * 16;
  const int agr = (bm + ar < M) ? (bm + ar) : (M - 1);
  const float* aptr = X + (size_t)agr * IN_C + acg;

  for (int kt = 0; kt < IN_C; kt += 64) {
#pragma unroll
    for (int p = 0; p < 8; ++p) {
      int s = p * 256 + tid;
      int r = s >> 3;
      int cb = s & 7;
      const unsigned short* g = Wb + (size_t)r * IN_C + kt + ((cb ^ (r & 7)) << 3);
      GLD_LDS16(g, &Bs[(p * 256 + wave * 64) * 8]);
    }
    float4 a0 = *(const float4*)(aptr + kt + 0);
    float4 a1 = *(const float4*)(aptr + kt + 4);
    float4 a2 = *(const float4*)(aptr + kt + 8);
    float4 a3 = *(const float4*)(aptr + kt + 12);
    union { uint4 u4[2]; __hip_bfloat162 h[8]; } pk;
    pk.h[0] = __float22bfloat162_rn(make_float2(a0.x, a0.y));
    pk.h[1] = __float22bfloat162_rn(make_float2(a0.z, a0.w));
    pk.h[2] = __float22bfloat162_rn(make_float2(a1.x, a1.y));
    pk.h[3] = __float22bfloat162_rn(make_float2(a1.z, a1.w));
    pk.h[4] = __float22bfloat162_rn(make_float2(a2.x, a2.y));
    pk.h[5] = __float22bfloat162_rn(make_float2(a2.z, a2.w));
    pk.h[6] = __float22bfloat162_rn(make_float2(a3.x, a3.y));
    pk.h[7] = __float22bfloat162_rn(make_float2(a3.z, a3.w));
    *(uint4*)&As[ar * LDTA + acg] = pk.u4[0];
    *(uint4*)&As[ar * LDTA + acg + 8] = pk.u4[1];
    __syncthreads();

#pragma unroll
    for (int k0 = 0; k0 < 64; k0 += 32) {
      bf16x8 af[4], bfr[4];
#pragma unroll
      for (int i = 0; i < 4; ++i)
        af[i] = *(const bf16x8*)&As[(i * 16 + m15) * LDTA + k0 + q * 8];
#pragma unroll
      for (int j = 0; j < 4; ++j) {
        int rb = wave * 64 + j * 16 + m15;
        int cbp = ((k0 >> 3) + q) ^ (rb & 7);
        bfr[j] = *(const bf16x8*)&Bs[rb * 64 + cbp * 8];
      }
#pragma unroll
      for (int i = 0; i < 4; ++i)
#pragma unroll
        for (int j = 0; j < 4; ++j)
          acc[i][j] = __builtin_amdgcn_mfma_f32_16x16x32_bf16(af[i], bfr[j], acc[i][j], 0, 0, 0);
    }
    __syncthreads();
  }
#pragma unroll
  for (int i = 0; i < 4; ++i) {
#pragma unroll
    for (int r = 0; r < 4; ++r) {
      int row = bm + i * 16 + q * 4 + r;
      if (row < M) {
#pragma unroll
        for (int j = 0; j < 4; ++j)
          Hb[(size_t)row * F1 + wave * 64 + j * 16 + m15] = bf16bits(acc[i][j][r]);
      }
    }
  }
}

// ---------------- GEMM (f32 VALU): C[M,N] = A[M,K] * B[N,K]^T  (layer 2) -----------
__global__ __launch_bounds__(256) void gemm_nt(const float* __restrict__ A,
                                               const float* __restrict__ B,
                                               float* __restrict__ C,
                                               int M, int N, int K) {
  __shared__ float As[32][68];
  __shared__ float Bs[32][68];
  const int bm = blockIdx.x * 64;
  const int bn = blockIdx.y * 64;
  const int tid = threadIdx.x;
  const int tx = tid & 15;
  const int ty = tid >> 4;
  float acc[4][4] = {{0.f, 0.f, 0.f, 0.f}};
  const int lr = tid >> 3;
  const int lc = (tid & 7) << 2;
  for (int kt = 0; kt < K; kt += 32) {
#pragma unroll
    for (int p = 0; p < 2; ++p) {
      int r = lr + p * 32;
      int gr = bm + r;
      float4 va = make_float4(0.f, 0.f, 0.f, 0.f);
      if (gr < M) va = *(const float4*)(A + (size_t)gr * K + kt + lc);
      As[lc + 0][r] = va.x; As[lc + 1][r] = va.y;
      As[lc + 2][r] = va.z; As[lc + 3][r] = va.w;
      int gn = bn + r;
      float4 vb = make_float4(0.f, 0.f, 0.f, 0.f);
      if (gn < N) vb = *(const float4*)(B + (size_t)gn * K + kt + lc);
      Bs[lc + 0][r] = vb.x; Bs[lc + 1][r] = vb.y;
      Bs[lc + 2][r] = vb.z; Bs[lc + 3][r] = vb.w;
    }
    __syncthreads();
#pragma unroll
    for (int k = 0; k < 32; ++k) {
      float4 a = *(const float4*)&As[k][ty * 4];
      float4 b = *(const float4*)&Bs[k][tx * 4];
      float av[4] = {a.x, a.y, a.z, a.w};
      float bv[4] = {b.x, b.y, b.z, b.w};
#pragma unroll
      for (int i = 0; i < 4; ++i)
#pragma unroll
        for (int j = 0; j < 4; ++j) acc[i][j] = fmaf(av[i], bv[j], acc[i][j]);
    }
    __syncthreads();
  }
#pragma unroll
  for (int i = 0; i < 4; ++i) {
    int row = bm + ty * 4 + i;
    if (row < M) {
#pragma unroll
      for (int j = 0; j < 4; ++j)
        C[(size_t)row * N + bn + tx * 4 + j] = acc[i][j];
    }
  }
}

// ---------------- CSR build ----------------
__global__ void degree_kernel(const int* __restrict__ ei, int E, int N,
                              int* __restrict__ deg) {
  int e = blockIdx.x * blockDim.x + threadIdx.x;
  if (e >= E + N) return;
  int dst = (e < E) ? ei[E + e] : (e - E);
  atomicAdd(&deg[dst], 1);
}

__global__ __launch_bounds__(256) void scan_block_sums(const int* __restrict__ deg,
                                                       int* __restrict__ part, int n) {
  __shared__ int sm[256];
  int t = threadIdx.x;
  int i = blockIdx.x * 256 + t;
  sm[t] = (i < n) ? deg[i] : 0;
  __syncthreads();
  for (int off = 128; off > 0; off >>= 1) {
    if (t < off) sm[t] += sm[t + off];
    __syncthreads();
  }
  if (t == 0) part[blockIdx.x] = sm[0];
}

__global__ __launch_bounds__(256) void scan_partials(int* __restrict__ part, int P) {
  __shared__ int sm[256];
  int t = threadIdx.x;
  int v = (t < P) ? part[t] : 0;
  sm[t] = v;
  __syncthreads();
  for (int off = 1; off < 256; off <<= 1) {
    int u = (t >= off) ? sm[t - off] : 0;
    __syncthreads();
    sm[t] += u;
    __syncthreads();
  }
  if (t < P) part[t] = sm[t];
}

__global__ __launch_bounds__(256) void scan_final(const int* __restrict__ deg,
                                                  const int* __restrict__ part,
                                                  int* __restrict__ row_ptr, int n) {
  __shared__ int sm[256];
  int t = threadIdx.x;
  int i = blockIdx.x * 256 + t;
  sm[t] = (i < n) ? deg[i] : 0;
  __syncthreads();
  for (int off = 1; off < 256; off <<= 1) {
    int u = (t >= off) ? sm[t - off] : 0;
    __syncthreads();
    sm[t] += u;
    __syncthreads();
  }
  int base = blockIdx.x ? part[blockIdx.x - 1] : 0;
  if (i < n) row_ptr[i + 1] = base + sm[t];
  if (i == 0) row_ptr[0] = 0;
}

__global__ void scatter_kernel(const int* __restrict__ ei, int E, int N,
                               const int* __restrict__ row_ptr, int* __restrict__ fill,
                               int* __restrict__ col) {
  int e = blockIdx.x * blockDim.x + threadIdx.x;
  if (e >= E + N) return;
  int src, dst;
  if (e < E) { src = ei[e]; dst = ei[E + e]; }
  else       { src = e - E; dst = e - E; }
  int pos = row_ptr[dst] + atomicAdd(&fill[dst], 1);
  col[pos] = src;
}

// ------- alpha dot-products from bf16 h (layer 1): one wave per node --------------
__global__ __launch_bounds__(256) void alpha_b_kernel(const unsigned short* __restrict__ hb,
                                                      const float* __restrict__ a_src,
                                                      const float* __restrict__ a_dst,
                                                      float* __restrict__ as_out,
                                                      float* __restrict__ ad_out, int N) {
  int w = (blockIdx.x * blockDim.x + threadIdx.x) >> 6;
  int lane = threadIdx.x & 63;
  if (w >= N) return;
  ushort4 hv = *(const ushort4*)(hb + (size_t)w * F1 + lane * 4);
  float v0 = bf2f(hv.x), v1 = bf2f(hv.y), v2 = bf2f(hv.z), v3 = bf2f(hv.w);
  int c = lane * 4;
  float4 asv = *(const float4*)(a_src + c);
  float4 adv = *(const float4*)(a_dst + c);
  float s = v0 * asv.x + v1 * asv.y + v2 * asv.z + v3 * asv.w;
  float d = v0 * adv.x + v1 * adv.y + v2 * adv.z + v3 * adv.w;
#pragma unroll
  for (int o = 1; o < 16; o <<= 1) {
    s += __shfl_xor(s, o, 64);
    d += __shfl_xor(d, o, 64);
  }
  if ((lane & 15) == 0) {
    int hh = lane >> 4;
    as_out[w * HEADS + hh] = s;
    ad_out[w * HEADS + hh] = d;
  }
}

// f32 variant for layer 2 (NH=1)
__global__ __launch_bounds__(256) void alpha1_kernel(const float* __restrict__ h,
                                                     const float* __restrict__ a_src,
                                                     const float* __restrict__ a_dst,
                                                     float* __restrict__ as_out,
                                                     float* __restrict__ ad_out, int N) {
  int w = (blockIdx.x * blockDim.x + threadIdx.x) >> 6;
  int lane = threadIdx.x & 63;
  if (w >= N) return;
  float v = h[(size_t)w * OUT_C + lane];
  float s = v * a_src[lane];
  float d = v * a_dst[lane];
#pragma unroll
  for (int o = 32; o > 0; o >>= 1) {
    s += __shfl_xor(s, o, 64);
    d += __shfl_xor(d, o, 64);
  }
  if (lane == 0) {
    as_out[w] = s;
    ad_out[w] = d;
  }
}

// ------- score kernel: per-dst wave; writes w = exp(e-m) in CSR order + inv --------
template <int NH>
__global__ __launch_bounds__(256) void score_kernel(const float* __restrict__ as,
                                                    const float* __restrict__ ad,
                                                    const int* __restrict__ row_ptr,
                                                    const int* __restrict__ col,
                                                    float* __restrict__ wgt,
                                                    float* __restrict__ inv, int N) {
  int dst = (blockIdx.x * blockDim.x + threadIdx.x) >> 6;
  int lane = threadIdx.x & 63;
  if (dst >= N) return;
  const int s0 = row_ptr[dst], s1 = row_ptr[dst + 1];
  float adl[NH];
#pragma unroll
  for (int hh = 0; hh < NH; ++hh) adl[hh] = ad[dst * NH + hh];

  float m[NH];
#pragma unroll
  for (int hh = 0; hh < NH; ++hh) m[hh] = -1e30f;
  for (int i = s0 + lane; i < s1; i += 64) {
    int s = col[i];
    if (NH == 4) {
      float4 a = *(const float4*)(as + (size_t)s * 4);
      float e0 = leaky(a.x + adl[0]), e1 = leaky(a.y + adl[1]);
      float e2 = leaky(a.z + adl[2]), e3 = leaky(a.w + adl[3]);
      *(float4*)(wgt + (size_t)i * 4) = make_float4(e0, e1, e2, e3);
      m[0] = fmaxf(m[0], e0); m[1] = fmaxf(m[1], e1);
      m[2] = fmaxf(m[2], e2); m[3] = fmaxf(m[3], e3);
    } else {
      float e = leaky(as[s] + adl[0]);
      wgt[i] = e;
      m[0] = fmaxf(m[0], e);
    }
  }
#pragma unroll
  for (int hh = 0; hh < NH; ++hh)
    for (int o = 32; o > 0; o >>= 1) m[hh] = fmaxf(m[hh], __shfl_xor(m[hh], o, 64));

  float den[NH];
#pragma unroll
  for (int hh = 0; hh < NH; ++hh) den[hh] = 0.f;
  for (int i = s0 + lane; i < s1; i += 64) {
    if (NH == 4) {
      float4 e = *(const float4*)(wgt + (size_t)i * 4);
      e.x = __expf(e.x - m[0]); e.y = __expf(e.y - m[1]);
      e.z = __expf(e.z - m[2]); e.w = __expf(e.w - m[3]);
      *(float4*)(wgt + (size_t)i * 4) = e;
      den[0] += e.x; den[1] += e.y; den[2] += e.z; den[3] += e.w;
    } else {
      float e = __expf(wgt[i] - m[0]);
      wgt[i] = e;
      den[0] += e;
    }
  }
#pragma unroll
  for (int hh = 0; hh < NH; ++hh)
    for (int o = 32; o > 0; o >>= 1) den[hh] += __shfl_xor(den[hh], o, 64);
  if (lane == 0) {
#pragma unroll
    for (int hh = 0; hh < NH; ++hh) inv[dst * NH + hh] = 1.f / den[hh];
  }
}

// ------- layer-1 aggregate: wave per dst, all 4 heads; bf16 h rows (512 B) ---------
__global__ __launch_bounds__(256) void agg1_kernel(const unsigned short* __restrict__ hb,
                                                   const float* __restrict__ wgt,
                                                   const float* __restrict__ inv,
                                                   const int* __restrict__ row_ptr,
                                                   const int* __restrict__ col,
                                                   const float* __restrict__ bias,
                                                   float* __restrict__ out, int N) {
  int dst = (blockIdx.x * blockDim.x + threadIdx.x) >> 6;
  int lane = threadIdx.x & 63;
  if (dst >= N) return;
  const int s0 = row_ptr[dst], s1 = row_ptr[dst + 1];
  const int q = lane >> 4;  // head for this lane's 4 channels
  float a0 = 0.f, a1 = 0.f, a2 = 0.f, a3 = 0.f;
  int i = s0;
  for (; i + 2 <= s1; i += 2) {
    int sA = col[i], sB = col[i + 1];
    float wA = wgt[(size_t)i * 4 + q];
    float wB = wgt[(size_t)(i + 1) * 4 + q];
    ushort4 hA = *(const ushort4*)(hb + (size_t)sA * F1 + lane * 4);
    ushort4 hB = *(const ushort4*)(hb + (size_t)sB * F1 + lane * 4);
    a0 = fmaf(wA, bf2f(hA.x), a0); a1 = fmaf(wA, bf2f(hA.y), a1);
    a2 = fmaf(wA, bf2f(hA.z), a2); a3 = fmaf(wA, bf2f(hA.w), a3);
    a0 = fmaf(wB, bf2f(hB.x), a0); a1 = fmaf(wB, bf2f(hB.y), a1);
    a2 = fmaf(wB, bf2f(hB.z), a2); a3 = fmaf(wB, bf2f(hB.w), a3);
  }
  for (; i < s1; ++i) {
    int s = col[i];
    float w = wgt[(size_t)i * 4 + q];
    ushort4 hv = *(const ushort4*)(hb + (size_t)s * F1 + lane * 4);
    a0 = fmaf(w, bf2f(hv.x), a0); a1 = fmaf(w, bf2f(hv.y), a1);
    a2 = fmaf(w, bf2f(hv.z), a2); a3 = fmaf(w, bf2f(hv.w), a3);
  }
  const float iv = inv[dst * 4 + q];
  float4 bv = *(const float4*)(bias + lane * 4);
  float v0 = a0 * iv + bv.x, v1 = a1 * iv + bv.y;
  float v2 = a2 * iv + bv.z, v3 = a3 * iv + bv.w;
  v0 = v0 > 0.f ? v0 : (__expf(v0) - 1.f);
  v1 = v1 > 0.f ? v1 : (__expf(v1) - 1.f);
  v2 = v2 > 0.f ? v2 : (__expf(v2) - 1.f);
  v3 = v3 > 0.f ? v3 : (__expf(v3) - 1.f);
  *(float4*)(out + (size_t)dst * F1 + lane * 4) = make_float4(v0, v1, v2, v3);
}

// ------- layer-2 aggregate: wave per dst, lane = channel; f32 h rows (256 B) -------
__global__ __launch_bounds__(256) void agg2_kernel(const float* __restrict__ h,
                                                   const float* __restrict__ wgt,
                                                   const float* __restrict__ inv,
                                                   const int* __restrict__ row_ptr,
                                                   const int* __restrict__ col,
                                                   const float* __restrict__ bias,
                                                   float* __restrict__ out, int N) {
  int dst = (blockIdx.x * blockDim.x + threadIdx.x) >> 6;
  int lane = threadIdx.x & 63;
  if (dst >= N) return;
  const int s0 = row_ptr[dst], s1 = row_ptr[dst + 1];
  float acc = 0.f;
  int i = s0;
  for (; i + 4 <= s1; i += 4) {
    int sA = col[i], sB = col[i + 1], sC = col[i + 2], sD = col[i + 3];
    float wA = wgt[i], wB = wgt[i + 1], wC = wgt[i + 2], wD = wgt[i + 3];
    float hA = h[(size_t)sA * OUT_C + lane];
    float hB = h[(size_t)sB * OUT_C + lane];
    float hC = h[(size_t)sC * OUT_C + lane];
    float hD = h[(size_t)sD * OUT_C + lane];
    acc = fmaf(wA, hA, acc); acc = fmaf(wB, hB, acc);
    acc = fmaf(wC, hC, acc); acc = fmaf(wD, hD, acc);
  }
  for (; i < s1; ++i) acc = fmaf(wgt[i], h[(size_t)col[i] * OUT_C + lane], acc);
  out[(size_t)dst * OUT_C + lane] = acc * inv[dst] + bias[lane];
}

extern "C" void kernel_launch(void* const* d_in, const int* in_sizes, int n_in,
                              void* d_out, int out_size, void* d_ws, size_t ws_size,
                              hipStream_t stream) {
  const float* x      = (const float*)d_in[0];
  const int*   ei     = (const int*)d_in[1];
  const float* W1     = (const float*)d_in[2];
  const float* a_src1 = (const float*)d_in[3];
  const float* a_dst1 = (const float*)d_in[4];
  const float* b1     = (const float*)d_in[5];
  const float* W2     = (const float*)d_in[6];
  const float* a_src2 = (const float*)d_in[7];
  const float* a_dst2 = (const float*)d_in[8];
  const float* b2     = (const float*)d_in[9];
  float* out = (float*)d_out;

  const int N = in_sizes[0] / IN_C;
  const int E = in_sizes[1] / 2;
  const int ET = E + N;

  char* ws = (char*)d_ws;
  size_t off = 0;
  auto alloc = [&](size_t bytes) -> void* {
    void* p = ws + off;
    off = (off + bytes + 255) & ~(size_t)255;
    return p;
  };
  unsigned short* h1b = (unsigned short*)alloc((size_t)N * F1 * 2);
  float* y1      = (float*)alloc((size_t)N * F1 * 4);
  float* h2      = (float*)alloc((size_t)N * OUT_C * 4);
  float* as1     = (float*)alloc((size_t)N * HEADS * 4);
  float* ad1     = (float*)alloc((size_t)N * HEADS * 4);
  float* as2     = (float*)alloc((size_t)N * 4);
  float* ad2     = (float*)alloc((size_t)N * 4);
  float* w1e     = (float*)alloc((size_t)ET * HEADS * 4);
  float* w2e     = (float*)alloc((size_t)ET * 4);
  float* inv1    = (float*)alloc((size_t)N * HEADS * 4);
  float* inv2    = (float*)alloc((size_t)N * 4);
  int*   deg     = (int*)alloc((size_t)N * 4);
  int*   row_ptr = (int*)alloc((size_t)(N + 1) * 4);
  int*   fill    = (int*)alloc((size_t)N * 4);
  int*   col     = (int*)alloc((size_t)ET * 4);
  int*   part    = (int*)alloc(1024 * 4);
  unsigned short* W1b = (unsigned short*)alloc((size_t)F1 * IN_C * 2);
  (void)off; (void)ws_size; (void)n_in; (void)out_size;

  hipMemsetAsync(deg, 0, (size_t)N * 4, stream);
  hipMemsetAsync(fill, 0, (size_t)N * 4, stream);

  cvt_bf16_kernel<<<(F1 * IN_C + 255) / 256, 256, 0, stream>>>(W1, W1b, F1 * IN_C);

  const int P = (N + 255) / 256;
  degree_kernel<<<(ET + 255) / 256, 256, 0, stream>>>(ei, E, N, deg);
  scan_block_sums<<<P, 256, 0, stream>>>(deg, part, N);
  scan_partials<<<1, 256, 0, stream>>>(part, P);
  scan_final<<<P, 256, 0, stream>>>(deg, part, row_ptr, N);
  scatter_kernel<<<(ET + 255) / 256, 256, 0, stream>>>(ei, E, N, row_ptr, fill, col);

  const int NB4 = (N + 3) / 4;  // 4 waves per 256-thread block

  // ---- layer 1 ----
  gemm1_mfma<<<(N + 63) / 64, 256, 0, stream>>>(x, W1b, h1b, N);
  alpha_b_kernel<<<NB4, 256, 0, stream>>>(h1b, a_src1, a_dst1, as1, ad1, N);
  score_kernel<HEADS><<<NB4, 256, 0, stream>>>(as1, ad1, row_ptr, col, w1e, inv1, N);
  agg1_kernel<<<NB4, 256, 0, stream>>>(h1b, w1e, inv1, row_ptr, col, b1, y1, N);

  // ---- layer 2 ----
  dim3 g2((N + 63) / 64, OUT_C / 64);
  gemm_nt<<<g2, 256, 0, stream>>>(y1, W2, h2, N, OUT_C, F1);
  alpha1_kernel<<<NB4, 256, 0, stream>>>(h2, a_src2, a_dst2, as2, ad2, N);
  score_kernel<1><<<NB4, 256, 0, stream>>>(as2, ad2, row_ptr, col, w2e, inv2, N);
  agg2_kernel<<<NB4, 256, 0, stream>>>(h2, w2e, inv2, row_ptr, col, b2, out, N);
}

// Round 5
// 559.251 us; speedup vs baseline: 1.6403x; 1.1170x over previous
//
#include <hip/hip_runtime.h>
#include <hip/hip_bf16.h>
#include <math.h>

constexpr int IN_C = 1024;
constexpr int HEADS = 4;
constexpr int F1 = 256;
constexpr int OUT_C = 64;
constexpr float NEG = 0.2f;

using bf16x8 = __attribute__((ext_vector_type(8))) short;
using f32x4 = __attribute__((ext_vector_type(4))) float;

__device__ __forceinline__ float leaky(float x) { return x > 0.f ? x : NEG * x; }

__device__ __forceinline__ unsigned short bf16bits(float v) {
  __hip_bfloat16 b = __float2bfloat16(v);
  return *reinterpret_cast<unsigned short*>(&b);
}
__device__ __forceinline__ float bf2f(unsigned short u) {
  union { unsigned u; float f; } c; c.u = (unsigned)u << 16; return c.f;
}

#define GLD_LDS16(g, l)                                                        \
  __builtin_amdgcn_global_load_lds(                                            \
      (const __attribute__((address_space(1))) void*)(g),                      \
      (__attribute__((address_space(3))) void*)(l), 16, 0, 0)

// ---------------- f32 -> bf16 convert ----------------
__global__ void cvt_bf16_kernel(const float* __restrict__ in,
                                unsigned short* __restrict__ out, int n) {
  int i = blockIdx.x * blockDim.x + threadIdx.x;
  if (i < n) out[i] = bf16bits(in[i]);
}

// ------- GEMM1: Hb[M,256] = X*W1^T (bf16 MFMA) + fused alpha dot-products ---------
constexpr int LDTA = 72;

__global__ __launch_bounds__(256, 2) void gemm1_mfma(const float* __restrict__ X,
                                                     const unsigned short* __restrict__ Wb,
                                                     unsigned short* __restrict__ Hb,
                                                     const float* __restrict__ a_src,
                                                     const float* __restrict__ a_dst,
                                                     float* __restrict__ as_out,
                                                     float* __restrict__ ad_out, int M) {
  __shared__ unsigned short As[64 * LDTA];
  __shared__ unsigned short Bs[256 * 64];
  const int tid = threadIdx.x;
  const int wave = tid >> 6;
  const int lane = tid & 63;
  const int m15 = lane & 15;
  const int q = lane >> 4;
  const int bm = blockIdx.x * 64;

  f32x4 acc[4][4];
#pragma unroll
  for (int i = 0; i < 4; ++i)
#pragma unroll
    for (int j = 0; j < 4; ++j) acc[i][j] = (f32x4){0.f, 0.f, 0.f, 0.f};

  const int ar = tid >> 2;
  const int acg = (tid & 3) * 16;
  const int agr = (bm + ar < M) ? (bm + ar) : (M - 1);
  const float* aptr = X + (size_t)agr * IN_C + acg;

  for (int kt = 0; kt < IN_C; kt += 64) {
#pragma unroll
    for (int p = 0; p < 8; ++p) {
      int s = p * 256 + tid;
      int r = s >> 3;
      int cb = s & 7;
      const unsigned short* g = Wb + (size_t)r * IN_C + kt + ((cb ^ (r & 7)) << 3);
      GLD_LDS16(g, &Bs[(p * 256 + wave * 64) * 8]);
    }
    float4 a0 = *(const float4*)(aptr + kt + 0);
    float4 a1 = *(const float4*)(aptr + kt + 4);
    float4 a2 = *(const float4*)(aptr + kt + 8);
    float4 a3 = *(const float4*)(aptr + kt + 12);
    union { uint4 u4[2]; __hip_bfloat162 h[8]; } pk;
    pk.h[0] = __float22bfloat162_rn(make_float2(a0.x, a0.y));
    pk.h[1] = __float22bfloat162_rn(make_float2(a0.z, a0.w));
    pk.h[2] = __float22bfloat162_rn(make_float2(a1.x, a1.y));
    pk.h[3] = __float22bfloat162_rn(make_float2(a1.z, a1.w));
    pk.h[4] = __float22bfloat162_rn(make_float2(a2.x, a2.y));
    pk.h[5] = __float22bfloat162_rn(make_float2(a2.z, a2.w));
    pk.h[6] = __float22bfloat162_rn(make_float2(a3.x, a3.y));
    pk.h[7] = __float22bfloat162_rn(make_float2(a3.z, a3.w));
    *(uint4*)&As[ar * LDTA + acg] = pk.u4[0];
    *(uint4*)&As[ar * LDTA + acg + 8] = pk.u4[1];
    __syncthreads();

#pragma unroll
    for (int k0 = 0; k0 < 64; k0 += 32) {
      bf16x8 af[4], bfr[4];
#pragma unroll
      for (int i = 0; i < 4; ++i)
        af[i] = *(const bf16x8*)&As[(i * 16 + m15) * LDTA + k0 + q * 8];
#pragma unroll
      for (int j = 0; j < 4; ++j) {
        int rb = wave * 64 + j * 16 + m15;
        int cbp = ((k0 >> 3) + q) ^ (rb & 7);
        bfr[j] = *(const bf16x8*)&Bs[rb * 64 + cbp * 8];
      }
#pragma unroll
      for (int i = 0; i < 4; ++i)
#pragma unroll
        for (int j = 0; j < 4; ++j)
          acc[i][j] = __builtin_amdgcn_mfma_f32_16x16x32_bf16(af[i], bfr[j], acc[i][j], 0, 0, 0);
    }
    __syncthreads();
  }
  // a_src/a_dst fragments for this wave's head (= wave): channel j*16 + m15
  float asf[4], adf[4];
#pragma unroll
  for (int j = 0; j < 4; ++j) {
    asf[j] = a_src[wave * 64 + j * 16 + m15];
    adf[j] = a_dst[wave * 64 + j * 16 + m15];
  }
#pragma unroll
  for (int i = 0; i < 4; ++i) {
#pragma unroll
    for (int r = 0; r < 4; ++r) {
      int row = bm + i * 16 + q * 4 + r;
      if (row < M) {
#pragma unroll
        for (int j = 0; j < 4; ++j)
          Hb[(size_t)row * F1 + wave * 64 + j * 16 + m15] = bf16bits(acc[i][j][r]);
      }
      // fused alpha: per-head dot over this head's 64 channels
      float s = acc[i][0][r] * asf[0] + acc[i][1][r] * asf[1] +
                acc[i][2][r] * asf[2] + acc[i][3][r] * asf[3];
      float d = acc[i][0][r] * adf[0] + acc[i][1][r] * adf[1] +
                acc[i][2][r] * adf[2] + acc[i][3][r] * adf[3];
#pragma unroll
      for (int o = 1; o < 16; o <<= 1) {
        s += __shfl_xor(s, o, 64);
        d += __shfl_xor(d, o, 64);
      }
      if (m15 == 0 && row < M) {
        as_out[row * HEADS + wave] = s;
        ad_out[row * HEADS + wave] = d;
      }
    }
  }
}

// ------- GEMM2: H2[M,64] = Y(bf16)*W2^T (bf16 MFMA) + fused alpha -----------------
__global__ __launch_bounds__(256, 4) void gemm2_mfma(const unsigned short* __restrict__ Y,
                                                     const unsigned short* __restrict__ W2b,
                                                     float* __restrict__ H2,
                                                     const float* __restrict__ a_src,
                                                     const float* __restrict__ a_dst,
                                                     float* __restrict__ as_out,
                                                     float* __restrict__ ad_out, int M) {
  __shared__ unsigned short As[64 * 64];  // 8KB, xor-swizzled linear
  __shared__ unsigned short Bs[64 * 64];  // 8KB
  const int tid = threadIdx.x;
  const int wave = tid >> 6;
  const int lane = tid & 63;
  const int m15 = lane & 15;
  const int q = lane >> 4;
  const int bm = blockIdx.x * 64;

  f32x4 acc[4];
#pragma unroll
  for (int j = 0; j < 4; ++j) acc[j] = (f32x4){0.f, 0.f, 0.f, 0.f};

  for (int kt = 0; kt < F1; kt += 64) {
#pragma unroll
    for (int p = 0; p < 2; ++p) {
      int s = p * 256 + tid;
      int r = s >> 3;
      int cb = s & 7;
      int colo = (cb ^ (r & 7)) << 3;
      int gr = (bm + r < M) ? (bm + r) : (M - 1);
      GLD_LDS16(Y + (size_t)gr * F1 + kt + colo, &As[(p * 256 + wave * 64) * 8]);
      GLD_LDS16(W2b + (size_t)r * F1 + kt + colo, &Bs[(p * 256 + wave * 64) * 8]);
    }
    __syncthreads();
#pragma unroll
    for (int k0 = 0; k0 < 64; k0 += 32) {
      int ra = wave * 16 + m15;
      bf16x8 af = *(const bf16x8*)&As[ra * 64 + ((((k0 >> 3) + q) ^ (ra & 7)) << 3)];
      bf16x8 bfr[4];
#pragma unroll
      for (int j = 0; j < 4; ++j) {
        int rb = j * 16 + m15;
        bfr[j] = *(const bf16x8*)&Bs[rb * 64 + ((((k0 >> 3) + q) ^ (rb & 7)) << 3)];
      }
#pragma unroll
      for (int j = 0; j < 4; ++j)
        acc[j] = __builtin_amdgcn_mfma_f32_16x16x32_bf16(af, bfr[j], acc[j], 0, 0, 0);
    }
    __syncthreads();
  }
  float asf[4], adf[4];
#pragma unroll
  for (int j = 0; j < 4; ++j) {
    asf[j] = a_src[j * 16 + m15];
    adf[j] = a_dst[j * 16 + m15];
  }
#pragma unroll
  for (int r = 0; r < 4; ++r) {
    int row = bm + wave * 16 + q * 4 + r;
    if (row < M) {
#pragma unroll
      for (int j = 0; j < 4; ++j) H2[(size_t)row * OUT_C + j * 16 + m15] = acc[j][r];
    }
    float s = acc[0][r] * asf[0] + acc[1][r] * asf[1] + acc[2][r] * asf[2] + acc[3][r] * asf[3];
    float d = acc[0][r] * adf[0] + acc[1][r] * adf[1] + acc[2][r] * adf[2] + acc[3][r] * adf[3];
#pragma unroll
    for (int o = 1; o < 16; o <<= 1) {
      s += __shfl_xor(s, o, 64);
      d += __shfl_xor(d, o, 64);
    }
    if (m15 == 0 && row < M) {
      as_out[row] = s;
      ad_out[row] = d;
    }
  }
}

// ---------------- CSR build ----------------
__global__ void degree_kernel(const int* __restrict__ ei, int E, int N,
                              int* __restrict__ deg) {
  int e = blockIdx.x * blockDim.x + threadIdx.x;
  if (e >= E + N) return;
  int dst = (e < E) ? ei[E + e] : (e - E);
  atomicAdd(&deg[dst], 1);
}

__global__ __launch_bounds__(256) void scan_block_sums(const int* __restrict__ deg,
                                                       int* __restrict__ part, int n) {
  __shared__ int sm[256];
  int t = threadIdx.x;
  int i = blockIdx.x * 256 + t;
  sm[t] = (i < n) ? deg[i] : 0;
  __syncthreads();
  for (int off = 128; off > 0; off >>= 1) {
    if (t < off) sm[t] += sm[t + off];
    __syncthreads();
  }
  if (t == 0) part[blockIdx.x] = sm[0];
}

__global__ __launch_bounds__(256) void scan_partials(int* __restrict__ part, int P) {
  __shared__ int sm[256];
  int t = threadIdx.x;
  int v = (t < P) ? part[t] : 0;
  sm[t] = v;
  __syncthreads();
  for (int off = 1; off < 256; off <<= 1) {
    int u = (t >= off) ? sm[t - off] : 0;
    __syncthreads();
    sm[t] += u;
    __syncthreads();
  }
  if (t < P) part[t] = sm[t];
}

__global__ __launch_bounds__(256) void scan_final(const int* __restrict__ deg,
                                                  const int* __restrict__ part,
                                                  int* __restrict__ row_ptr, int n) {
  __shared__ int sm[256];
  int t = threadIdx.x;
  int i = blockIdx.x * 256 + t;
  sm[t] = (i < n) ? deg[i] : 0;
  __syncthreads();
  for (int off = 1; off < 256; off <<= 1) {
    int u = (t >= off) ? sm[t - off] : 0;
    __syncthreads();
    sm[t] += u;
    __syncthreads();
  }
  int base = blockIdx.x ? part[blockIdx.x - 1] : 0;
  if (i < n) row_ptr[i + 1] = base + sm[t];
  if (i == 0) row_ptr[0] = 0;
}

__global__ void scatter_kernel(const int* __restrict__ ei, int E, int N,
                               const int* __restrict__ row_ptr, int* __restrict__ fill,
                               int* __restrict__ col) {
  int e = blockIdx.x * blockDim.x + threadIdx.x;
  if (e >= E + N) return;
  int src, dst;
  if (e < E) { src = ei[e]; dst = ei[E + e]; }
  else       { src = e - E; dst = e - E; }
  int pos = row_ptr[dst] + atomicAdd(&fill[dst], 1);
  col[pos] = src;
}

// ------- layer-1 fused softmax+aggregate: wave/dst, no max, single pass ------------
// lane q=head, channels (lane&15)*4 within head. Output y1 in BF16.
__global__ __launch_bounds__(256) void agg1_kernel(const unsigned short* __restrict__ hb,
                                                   const float* __restrict__ as,
                                                   const float* __restrict__ ad,
                                                   const int* __restrict__ row_ptr,
                                                   const int* __restrict__ col,
                                                   const float* __restrict__ bias,
                                                   unsigned short* __restrict__ yb, int N) {
  int dst = (blockIdx.x * blockDim.x + threadIdx.x) >> 6;
  int lane = threadIdx.x & 63;
  if (dst >= N) return;
  const int s0 = row_ptr[dst], s1 = row_ptr[dst + 1];
  const int q = lane >> 4;
  const float adl = ad[dst * 4 + q];
  float a0 = 0.f, a1 = 0.f, a2 = 0.f, a3 = 0.f, den = 0.f;
  int i = s0;
  for (; i + 2 <= s1; i += 2) {
    int sA = col[i], sB = col[i + 1];
    float wA = __expf(leaky(as[sA * 4 + q] + adl));
    float wB = __expf(leaky(as[sB * 4 + q] + adl));
    ushort4 hA = *(const ushort4*)(hb + (size_t)sA * F1 + lane * 4);
    ushort4 hB = *(const ushort4*)(hb + (size_t)sB * F1 + lane * 4);
    den += wA + wB;
    a0 = fmaf(wA, bf2f(hA.x), a0); a1 = fmaf(wA, bf2f(hA.y), a1);
    a2 = fmaf(wA, bf2f(hA.z), a2); a3 = fmaf(wA, bf2f(hA.w), a3);
    a0 = fmaf(wB, bf2f(hB.x), a0); a1 = fmaf(wB, bf2f(hB.y), a1);
    a2 = fmaf(wB, bf2f(hB.z), a2); a3 = fmaf(wB, bf2f(hB.w), a3);
  }
  for (; i < s1; ++i) {
    int s = col[i];
    float w = __expf(leaky(as[s * 4 + q] + adl));
    ushort4 hv = *(const ushort4*)(hb + (size_t)s * F1 + lane * 4);
    den += w;
    a0 = fmaf(w, bf2f(hv.x), a0); a1 = fmaf(w, bf2f(hv.y), a1);
    a2 = fmaf(w, bf2f(hv.z), a2); a3 = fmaf(w, bf2f(hv.w), a3);
  }
  const float iv = 1.f / den;
  float4 bv = *(const float4*)(bias + lane * 4);
  float v0 = a0 * iv + bv.x, v1 = a1 * iv + bv.y;
  float v2 = a2 * iv + bv.z, v3 = a3 * iv + bv.w;
  v0 = v0 > 0.f ? v0 : (__expf(v0) - 1.f);
  v1 = v1 > 0.f ? v1 : (__expf(v1) - 1.f);
  v2 = v2 > 0.f ? v2 : (__expf(v2) - 1.f);
  v3 = v3 > 0.f ? v3 : (__expf(v3) - 1.f);
  ushort4 o;
  o.x = bf16bits(v0); o.y = bf16bits(v1); o.z = bf16bits(v2); o.w = bf16bits(v3);
  *(ushort4*)(yb + (size_t)dst * F1 + lane * 4) = o;
}

// ------- layer-2 fused softmax+aggregate: wave/dst, lane = channel -----------------
__global__ __launch_bounds__(256) void agg2_kernel(const float* __restrict__ h,
                                                   const float* __restrict__ as,
                                                   const float* __restrict__ ad,
                                                   const int* __restrict__ row_ptr,
                                                   const int* __restrict__ col,
                                                   const float* __restrict__ bias,
                                                   float* __restrict__ out, int N) {
  int dst = (blockIdx.x * blockDim.x + threadIdx.x) >> 6;
  int lane = threadIdx.x & 63;
  if (dst >= N) return;
  const int s0 = row_ptr[dst], s1 = row_ptr[dst + 1];
  const float adl = ad[dst];
  float acc = 0.f, den = 0.f;
  int i = s0;
  for (; i + 2 <= s1; i += 2) {
    int sA = col[i], sB = col[i + 1];
    float wA = __expf(leaky(as[sA] + adl));
    float wB = __expf(leaky(as[sB] + adl));
    float hA = h[(size_t)sA * OUT_C + lane];
    float hB = h[(size_t)sB * OUT_C + lane];
    den += wA + wB;
    acc = fmaf(wA, hA, acc);
    acc = fmaf(wB, hB, acc);
  }
  for (; i < s1; ++i) {
    int s = col[i];
    float w = __expf(leaky(as[s] + adl));
    den += w;
    acc = fmaf(w, h[(size_t)s * OUT_C + lane], acc);
  }
  out[(size_t)dst * OUT_C + lane] = acc / den + bias[lane];
}

extern "C" void kernel_launch(void* const* d_in, const int* in_sizes, int n_in,
                              void* d_out, int out_size, void* d_ws, size_t ws_size,
                              hipStream_t stream) {
  const float* x      = (const float*)d_in[0];
  const int*   ei     = (const int*)d_in[1];
  const float* W1     = (const float*)d_in[2];
  const float* a_src1 = (const float*)d_in[3];
  const float* a_dst1 = (const float*)d_in[4];
  const float* b1     = (const float*)d_in[5];
  const float* W2     = (const float*)d_in[6];
  const float* a_src2 = (const float*)d_in[7];
  const float* a_dst2 = (const float*)d_in[8];
  const float* b2     = (const float*)d_in[9];
  float* out = (float*)d_out;

  const int N = in_sizes[0] / IN_C;
  const int E = in_sizes[1] / 2;
  const int ET = E + N;

  char* ws = (char*)d_ws;
  size_t off = 0;
  auto alloc = [&](size_t bytes) -> void* {
    void* p = ws + off;
    off = (off + bytes + 255) & ~(size_t)255;
    return p;
  };
  unsigned short* h1b = (unsigned short*)alloc((size_t)N * F1 * 2);
  unsigned short* y1b = (unsigned short*)alloc((size_t)N * F1 * 2);
  float* h2      = (float*)alloc((size_t)N * OUT_C * 4);
  float* as1     = (float*)alloc((size_t)N * HEADS * 4);
  float* ad1     = (float*)alloc((size_t)N * HEADS * 4);
  float* as2     = (float*)alloc((size_t)N * 4);
  float* ad2     = (float*)alloc((size_t)N * 4);
  int*   deg     = (int*)alloc((size_t)N * 4);
  int*   row_ptr = (int*)alloc((size_t)(N + 1) * 4);
  int*   fill    = (int*)alloc((size_t)N * 4);
  int*   col     = (int*)alloc((size_t)ET * 4);
  int*   part    = (int*)alloc(1024 * 4);
  unsigned short* W1b = (unsigned short*)alloc((size_t)F1 * IN_C * 2);
  unsigned short* W2b = (unsigned short*)alloc((size_t)OUT_C * F1 * 2);
  (void)off; (void)ws_size; (void)n_in; (void)out_size;

  hipMemsetAsync(deg, 0, (size_t)N * 4, stream);
  hipMemsetAsync(fill, 0, (size_t)N * 4, stream);

  cvt_bf16_kernel<<<(F1 * IN_C + 255) / 256, 256, 0, stream>>>(W1, W1b, F1 * IN_C);
  cvt_bf16_kernel<<<(OUT_C * F1 + 255) / 256, 256, 0, stream>>>(W2, W2b, OUT_C * F1);

  const int P = (N + 255) / 256;
  degree_kernel<<<(ET + 255) / 256, 256, 0, stream>>>(ei, E, N, deg);
  scan_block_sums<<<P, 256, 0, stream>>>(deg, part, N);
  scan_partials<<<1, 256, 0, stream>>>(part, P);
  scan_final<<<P, 256, 0, stream>>>(deg, part, row_ptr, N);
  scatter_kernel<<<(ET + 255) / 256, 256, 0, stream>>>(ei, E, N, row_ptr, fill, col);

  const int NB4 = (N + 3) / 4;

  // ---- layer 1 ----
  gemm1_mfma<<<(N + 63) / 64, 256, 0, stream>>>(x, W1b, h1b, a_src1, a_dst1, as1, ad1, N);
  agg1_kernel<<<NB4, 256, 0, stream>>>(h1b, as1, ad1, row_ptr, col, b1, y1b, N);

  // ---- layer 2 ----
  gemm2_mfma<<<(N + 63) / 64, 256, 0, stream>>>(y1b, W2b, h2, a_src2, a_dst2, as2, ad2, N);
  agg2_kernel<<<NB4, 256, 0, stream>>>(h2, as2, ad2, row_ptr, col, b2, out, N);
}

// Round 6
// 540.639 us; speedup vs baseline: 1.6968x; 1.0344x over previous
//
#include <hip/hip_runtime.h>
#include <hip/hip_bf16.h>
#include <math.h>

constexpr int IN_C = 1024;
constexpr int HEADS = 4;
constexpr int F1 = 256;
constexpr int OUT_C = 64;
constexpr float NEG = 0.2f;

using bf16x8 = __attribute__((ext_vector_type(8))) short;
using f32x4 = __attribute__((ext_vector_type(4))) float;

__device__ __forceinline__ float leaky(float x) { return x > 0.f ? x : NEG * x; }

__device__ __forceinline__ unsigned short bf16bits(float v) {
  __hip_bfloat16 b = __float2bfloat16(v);
  return *reinterpret_cast<unsigned short*>(&b);
}
__device__ __forceinline__ float bf2f(unsigned short u) {
  union { unsigned u; float f; } c; c.u = (unsigned)u << 16; return c.f;
}

#define GLD_LDS16(g, l)                                                        \
  __builtin_amdgcn_global_load_lds(                                            \
      (const __attribute__((address_space(1))) void*)(g),                      \
      (__attribute__((address_space(3))) void*)(l), 16, 0, 0)

// ---------------- f32 -> bf16 convert ----------------
__global__ void cvt_bf16_kernel(const float* __restrict__ in,
                                unsigned short* __restrict__ out, int n) {
  int i = blockIdx.x * blockDim.x + threadIdx.x;
  if (i < n) out[i] = bf16bits(in[i]);
}

// ------- GEMM1: Hb[M,256] = X*W1^T (bf16 MFMA) + fused alpha dot-products ---------
constexpr int LDTA = 72;

__global__ __launch_bounds__(256, 2) void gemm1_mfma(const float* __restrict__ X,
                                                     const unsigned short* __restrict__ Wb,
                                                     unsigned short* __restrict__ Hb,
                                                     const float* __restrict__ a_src,
                                                     const float* __restrict__ a_dst,
                                                     float* __restrict__ as_out,
                                                     float* __restrict__ ad_out, int M) {
  __shared__ unsigned short As[64 * LDTA];
  __shared__ unsigned short Bs[256 * 64];
  const int tid = threadIdx.x;
  const int wave = tid >> 6;
  const int lane = tid & 63;
  const int m15 = lane & 15;
  const int q = lane >> 4;
  const int bm = blockIdx.x * 64;

  f32x4 acc[4][4];
#pragma unroll
  for (int i = 0; i < 4; ++i)
#pragma unroll
    for (int j = 0; j < 4; ++j) acc[i][j] = (f32x4){0.f, 0.f, 0.f, 0.f};

  const int ar = tid >> 2;
  const int acg = (tid & 3) * 16;
  const int agr = (bm + ar < M) ? (bm + ar) : (M - 1);
  const float* aptr = X + (size_t)agr * IN_C + acg;

  for (int kt = 0; kt < IN_C; kt += 64) {
    // A global loads first (HBM, longest latency)
    float4 a0 = *(const float4*)(aptr + kt + 0);
    float4 a1 = *(const float4*)(aptr + kt + 4);
    float4 a2 = *(const float4*)(aptr + kt + 8);
    float4 a3 = *(const float4*)(aptr + kt + 12);
    // B staging (L2-resident after first touch)
#pragma unroll
    for (int p = 0; p < 8; ++p) {
      int s = p * 256 + tid;
      int r = s >> 3;
      int cb = s & 7;
      const unsigned short* g = Wb + (size_t)r * IN_C + kt + ((cb ^ (r & 7)) << 3);
      GLD_LDS16(g, &Bs[(p * 256 + wave * 64) * 8]);
    }
    union { uint4 u4[2]; __hip_bfloat162 h[8]; } pk;
    pk.h[0] = __float22bfloat162_rn(make_float2(a0.x, a0.y));
    pk.h[1] = __float22bfloat162_rn(make_float2(a0.z, a0.w));
    pk.h[2] = __float22bfloat162_rn(make_float2(a1.x, a1.y));
    pk.h[3] = __float22bfloat162_rn(make_float2(a1.z, a1.w));
    pk.h[4] = __float22bfloat162_rn(make_float2(a2.x, a2.y));
    pk.h[5] = __float22bfloat162_rn(make_float2(a2.z, a2.w));
    pk.h[6] = __float22bfloat162_rn(make_float2(a3.x, a3.y));
    pk.h[7] = __float22bfloat162_rn(make_float2(a3.z, a3.w));
    *(uint4*)&As[ar * LDTA + acg] = pk.u4[0];
    *(uint4*)&As[ar * LDTA + acg + 8] = pk.u4[1];
    __syncthreads();

#pragma unroll
    for (int k0 = 0; k0 < 64; k0 += 32) {
      bf16x8 af[4], bfr[4];
#pragma unroll
      for (int i = 0; i < 4; ++i)
        af[i] = *(const bf16x8*)&As[(i * 16 + m15) * LDTA + k0 + q * 8];
#pragma unroll
      for (int j = 0; j < 4; ++j) {
        int rb = wave * 64 + j * 16 + m15;
        int cbp = ((k0 >> 3) + q) ^ (rb & 7);
        bfr[j] = *(const bf16x8*)&Bs[rb * 64 + cbp * 8];
      }
#pragma unroll
      for (int i = 0; i < 4; ++i)
#pragma unroll
        for (int j = 0; j < 4; ++j)
          acc[i][j] = __builtin_amdgcn_mfma_f32_16x16x32_bf16(af[i], bfr[j], acc[i][j], 0, 0, 0);
    }
    __syncthreads();
  }
  float asf[4], adf[4];
#pragma unroll
  for (int j = 0; j < 4; ++j) {
    asf[j] = a_src[wave * 64 + j * 16 + m15];
    adf[j] = a_dst[wave * 64 + j * 16 + m15];
  }
#pragma unroll
  for (int i = 0; i < 4; ++i) {
#pragma unroll
    for (int r = 0; r < 4; ++r) {
      int row = bm + i * 16 + q * 4 + r;
      if (row < M) {
#pragma unroll
        for (int j = 0; j < 4; ++j)
          Hb[(size_t)row * F1 + wave * 64 + j * 16 + m15] = bf16bits(acc[i][j][r]);
      }
      float s = acc[i][0][r] * asf[0] + acc[i][1][r] * asf[1] +
                acc[i][2][r] * asf[2] + acc[i][3][r] * asf[3];
      float d = acc[i][0][r] * adf[0] + acc[i][1][r] * adf[1] +
                acc[i][2][r] * adf[2] + acc[i][3][r] * adf[3];
#pragma unroll
      for (int o = 1; o < 16; o <<= 1) {
        s += __shfl_xor(s, o, 64);
        d += __shfl_xor(d, o, 64);
      }
      if (m15 == 0 && row < M) {
        as_out[row * HEADS + wave] = s;
        ad_out[row * HEADS + wave] = d;
      }
    }
  }
}

// ------- GEMM2: H2[M,64] = Y(bf16)*W2^T (bf16 MFMA) + fused alpha -----------------
__global__ __launch_bounds__(256, 4) void gemm2_mfma(const unsigned short* __restrict__ Y,
                                                     const unsigned short* __restrict__ W2b,
                                                     float* __restrict__ H2,
                                                     const float* __restrict__ a_src,
                                                     const float* __restrict__ a_dst,
                                                     float* __restrict__ as_out,
                                                     float* __restrict__ ad_out, int M) {
  __shared__ unsigned short As[64 * 64];
  __shared__ unsigned short Bs[64 * 64];
  const int tid = threadIdx.x;
  const int wave = tid >> 6;
  const int lane = tid & 63;
  const int m15 = lane & 15;
  const int q = lane >> 4;
  const int bm = blockIdx.x * 64;

  f32x4 acc[4];
#pragma unroll
  for (int j = 0; j < 4; ++j) acc[j] = (f32x4){0.f, 0.f, 0.f, 0.f};

  for (int kt = 0; kt < F1; kt += 64) {
#pragma unroll
    for (int p = 0; p < 2; ++p) {
      int s = p * 256 + tid;
      int r = s >> 3;
      int cb = s & 7;
      int colo = (cb ^ (r & 7)) << 3;
      int gr = (bm + r < M) ? (bm + r) : (M - 1);
      GLD_LDS16(Y + (size_t)gr * F1 + kt + colo, &As[(p * 256 + wave * 64) * 8]);
      GLD_LDS16(W2b + (size_t)r * F1 + kt + colo, &Bs[(p * 256 + wave * 64) * 8]);
    }
    __syncthreads();
#pragma unroll
    for (int k0 = 0; k0 < 64; k0 += 32) {
      int ra = wave * 16 + m15;
      bf16x8 af = *(const bf16x8*)&As[ra * 64 + ((((k0 >> 3) + q) ^ (ra & 7)) << 3)];
      bf16x8 bfr[4];
#pragma unroll
      for (int j = 0; j < 4; ++j) {
        int rb = j * 16 + m15;
        bfr[j] = *(const bf16x8*)&Bs[rb * 64 + ((((k0 >> 3) + q) ^ (rb & 7)) << 3)];
      }
#pragma unroll
      for (int j = 0; j < 4; ++j)
        acc[j] = __builtin_amdgcn_mfma_f32_16x16x32_bf16(af, bfr[j], acc[j], 0, 0, 0);
    }
    __syncthreads();
  }
  float asf[4], adf[4];
#pragma unroll
  for (int j = 0; j < 4; ++j) {
    asf[j] = a_src[j * 16 + m15];
    adf[j] = a_dst[j * 16 + m15];
  }
#pragma unroll
  for (int r = 0; r < 4; ++r) {
    int row = bm + wave * 16 + q * 4 + r;
    if (row < M) {
#pragma unroll
      for (int j = 0; j < 4; ++j) H2[(size_t)row * OUT_C + j * 16 + m15] = acc[j][r];
    }
    float s = acc[0][r] * asf[0] + acc[1][r] * asf[1] + acc[2][r] * asf[2] + acc[3][r] * asf[3];
    float d = acc[0][r] * adf[0] + acc[1][r] * adf[1] + acc[2][r] * adf[2] + acc[3][r] * adf[3];
#pragma unroll
    for (int o = 1; o < 16; o <<= 1) {
      s += __shfl_xor(s, o, 64);
      d += __shfl_xor(d, o, 64);
    }
    if (m15 == 0 && row < M) {
      as_out[row] = s;
      ad_out[row] = d;
    }
  }
}

// ---------------- CSR build ----------------
__global__ void degree_kernel(const int* __restrict__ ei, int E, int N,
                              int* __restrict__ deg) {
  int e = blockIdx.x * blockDim.x + threadIdx.x;
  if (e >= E + N) return;
  int dst = (e < E) ? ei[E + e] : (e - E);
  atomicAdd(&deg[dst], 1);
}

__global__ __launch_bounds__(256) void scan_block_sums(const int* __restrict__ deg,
                                                       int* __restrict__ part, int n) {
  __shared__ int sm[256];
  int t = threadIdx.x;
  int i = blockIdx.x * 256 + t;
  sm[t] = (i < n) ? deg[i] : 0;
  __syncthreads();
  for (int off = 128; off > 0; off >>= 1) {
    if (t < off) sm[t] += sm[t + off];
    __syncthreads();
  }
  if (t == 0) part[blockIdx.x] = sm[0];
}

__global__ __launch_bounds__(256) void scan_partials(int* __restrict__ part, int P) {
  __shared__ int sm[256];
  int t = threadIdx.x;
  int v = (t < P) ? part[t] : 0;
  sm[t] = v;
  __syncthreads();
  for (int off = 1; off < 256; off <<= 1) {
    int u = (t >= off) ? sm[t - off] : 0;
    __syncthreads();
    sm[t] += u;
    __syncthreads();
  }
  if (t < P) part[t] = sm[t];
}

__global__ __launch_bounds__(256) void scan_final(const int* __restrict__ deg,
                                                  const int* __restrict__ part,
                                                  int* __restrict__ row_ptr, int n) {
  __shared__ int sm[256];
  int t = threadIdx.x;
  int i = blockIdx.x * 256 + t;
  sm[t] = (i < n) ? deg[i] : 0;
  __syncthreads();
  for (int off = 1; off < 256; off <<= 1) {
    int u = (t >= off) ? sm[t - off] : 0;
    __syncthreads();
    sm[t] += u;
    __syncthreads();
  }
  int base = blockIdx.x ? part[blockIdx.x - 1] : 0;
  if (i < n) row_ptr[i + 1] = base + sm[t];
  if (i == 0) row_ptr[0] = 0;
}

__global__ void scatter_kernel(const int* __restrict__ ei, int E, int N,
                               const int* __restrict__ row_ptr, int* __restrict__ fill,
                               int* __restrict__ col) {
  int e = blockIdx.x * blockDim.x + threadIdx.x;
  if (e >= E + N) return;
  int src, dst;
  if (e < E) { src = ei[e]; dst = ei[E + e]; }
  else       { src = e - E; dst = e - E; }
  int pos = row_ptr[dst] + atomicAdd(&fill[dst], 1);
  col[pos] = src;
}

// ------- layer-1 aggregate: wave/dst, TWO edges in flight (32-lane halves) ---------
// lane&31 = channel-group (8 ch, uint4), lane>>5 = edge parity; head = (lane&31)>>3.
__global__ __launch_bounds__(256) void agg1_kernel(const unsigned short* __restrict__ hb,
                                                   const float* __restrict__ as,
                                                   const float* __restrict__ ad,
                                                   const int* __restrict__ row_ptr,
                                                   const int* __restrict__ col,
                                                   const float* __restrict__ bias,
                                                   unsigned short* __restrict__ yb, int N) {
  int dst = (blockIdx.x * blockDim.x + threadIdx.x) >> 6;
  int lane = threadIdx.x & 63;
  if (dst >= N) return;
  const int s0 = row_ptr[dst], s1 = row_ptr[dst + 1];
  const int par = lane >> 5;
  const int cg = lane & 31;
  const int hh = cg >> 3;
  const float adl = ad[dst * 4 + hh];
  float acc[8];
#pragma unroll
  for (int k = 0; k < 8; ++k) acc[k] = 0.f;
  float den = 0.f;

  int i = s0 + par;
  for (; i + 2 < s1; i += 4) {  // 2 edges per parity per iter -> 4 rows in flight
    int sA = col[i], sB = col[i + 2];
    float wA = __expf(leaky(as[sA * 4 + hh] + adl));
    float wB = __expf(leaky(as[sB * 4 + hh] + adl));
    uint4 hA = *(const uint4*)(hb + (size_t)sA * F1 + cg * 8);
    uint4 hB = *(const uint4*)(hb + (size_t)sB * F1 + cg * 8);
    den += wA + wB;
    const unsigned short* pa = (const unsigned short*)&hA;
    const unsigned short* pb = (const unsigned short*)&hB;
#pragma unroll
    for (int k = 0; k < 8; ++k) {
      acc[k] = fmaf(wA, bf2f(pa[k]), acc[k]);
      acc[k] = fmaf(wB, bf2f(pb[k]), acc[k]);
    }
  }
  for (; i < s1; i += 2) {
    int s = col[i];
    float w = __expf(leaky(as[s * 4 + hh] + adl));
    uint4 hv = *(const uint4*)(hb + (size_t)s * F1 + cg * 8);
    den += w;
    const unsigned short* p = (const unsigned short*)&hv;
#pragma unroll
    for (int k = 0; k < 8; ++k) acc[k] = fmaf(w, bf2f(p[k]), acc[k]);
  }
  // combine the two parities
  den += __shfl_xor(den, 32, 64);
#pragma unroll
  for (int k = 0; k < 8; ++k) acc[k] += __shfl_xor(acc[k], 32, 64);

  if (par == 0) {
    const float iv = 1.f / den;
    float4 b0 = *(const float4*)(bias + cg * 8);
    float4 b1 = *(const float4*)(bias + cg * 8 + 4);
    float bv[8] = {b0.x, b0.y, b0.z, b0.w, b1.x, b1.y, b1.z, b1.w};
    ushort4 o[2];
    unsigned short* po = (unsigned short*)o;
#pragma unroll
    for (int k = 0; k < 8; ++k) {
      float v = acc[k] * iv + bv[k];
      v = v > 0.f ? v : (__expf(v) - 1.f);
      po[k] = bf16bits(v);
    }
    *(uint4*)(yb + (size_t)dst * F1 + cg * 8) = *(uint4*)o;
  }
}

// ------- layer-2 aggregate: wave/dst, two edges in flight; lane&31 -> 2 f32 ch -----
__global__ __launch_bounds__(256) void agg2_kernel(const float* __restrict__ h,
                                                   const float* __restrict__ as,
                                                   const float* __restrict__ ad,
                                                   const int* __restrict__ row_ptr,
                                                   const int* __restrict__ col,
                                                   const float* __restrict__ bias,
                                                   float* __restrict__ out, int N) {
  int dst = (blockIdx.x * blockDim.x + threadIdx.x) >> 6;
  int lane = threadIdx.x & 63;
  if (dst >= N) return;
  const int s0 = row_ptr[dst], s1 = row_ptr[dst + 1];
  const int par = lane >> 5;
  const int cg = lane & 31;
  const float adl = ad[dst];
  float a0 = 0.f, a1 = 0.f, den = 0.f;

  int i = s0 + par;
  for (; i + 2 < s1; i += 4) {
    int sA = col[i], sB = col[i + 2];
    float wA = __expf(leaky(as[sA] + adl));
    float wB = __expf(leaky(as[sB] + adl));
    float2 hA = *(const float2*)(h + (size_t)sA * OUT_C + cg * 2);
    float2 hB = *(const float2*)(h + (size_t)sB * OUT_C + cg * 2);
    den += wA + wB;
    a0 = fmaf(wA, hA.x, a0); a1 = fmaf(wA, hA.y, a1);
    a0 = fmaf(wB, hB.x, a0); a1 = fmaf(wB, hB.y, a1);
  }
  for (; i < s1; i += 2) {
    int s = col[i];
    float w = __expf(leaky(as[s] + adl));
    float2 hv = *(const float2*)(h + (size_t)s * OUT_C + cg * 2);
    den += w;
    a0 = fmaf(w, hv.x, a0); a1 = fmaf(w, hv.y, a1);
  }
  den += __shfl_xor(den, 32, 64);
  a0 += __shfl_xor(a0, 32, 64);
  a1 += __shfl_xor(a1, 32, 64);
  if (par == 0) {
    const float iv = 1.f / den;
    float2 bv = *(const float2*)(bias + cg * 2);
    float2 o = make_float2(a0 * iv + bv.x, a1 * iv + bv.y);
    *(float2*)(out + (size_t)dst * OUT_C + cg * 2) = o;
  }
}

extern "C" void kernel_launch(void* const* d_in, const int* in_sizes, int n_in,
                              void* d_out, int out_size, void* d_ws, size_t ws_size,
                              hipStream_t stream) {
  const float* x      = (const float*)d_in[0];
  const int*   ei     = (const int*)d_in[1];
  const float* W1     = (const float*)d_in[2];
  const float* a_src1 = (const float*)d_in[3];
  const float* a_dst1 = (const float*)d_in[4];
  const float* b1     = (const float*)d_in[5];
  const float* W2     = (const float*)d_in[6];
  const float* a_src2 = (const float*)d_in[7];
  const float* a_dst2 = (const float*)d_in[8];
  const float* b2     = (const float*)d_in[9];
  float* out = (float*)d_out;

  const int N = in_sizes[0] / IN_C;
  const int E = in_sizes[1] / 2;
  const int ET = E + N;

  char* ws = (char*)d_ws;
  size_t off = 0;
  auto alloc = [&](size_t bytes) -> void* {
    void* p = ws + off;
    off = (off + bytes + 255) & ~(size_t)255;
    return p;
  };
  unsigned short* h1b = (unsigned short*)alloc((size_t)N * F1 * 2);
  unsigned short* y1b = (unsigned short*)alloc((size_t)N * F1 * 2);
  float* h2      = (float*)alloc((size_t)N * OUT_C * 4);
  float* as1     = (float*)alloc((size_t)N * HEADS * 4);
  float* ad1     = (float*)alloc((size_t)N * HEADS * 4);
  float* as2     = (float*)alloc((size_t)N * 4);
  float* ad2     = (float*)alloc((size_t)N * 4);
  int*   deg     = (int*)alloc((size_t)N * 4);
  int*   row_ptr = (int*)alloc((size_t)(N + 1) * 4);
  int*   fill    = (int*)alloc((size_t)N * 4);
  int*   col     = (int*)alloc((size_t)ET * 4);
  int*   part    = (int*)alloc(1024 * 4);
  unsigned short* W1b = (unsigned short*)alloc((size_t)F1 * IN_C * 2);
  unsigned short* W2b = (unsigned short*)alloc((size_t)OUT_C * F1 * 2);
  (void)off; (void)ws_size; (void)n_in; (void)out_size;

  hipMemsetAsync(deg, 0, (size_t)N * 4, stream);
  hipMemsetAsync(fill, 0, (size_t)N * 4, stream);

  cvt_bf16_kernel<<<(F1 * IN_C + 255) / 256, 256, 0, stream>>>(W1, W1b, F1 * IN_C);
  cvt_bf16_kernel<<<(OUT_C * F1 + 255) / 256, 256, 0, stream>>>(W2, W2b, OUT_C * F1);

  const int P = (N + 255) / 256;
  degree_kernel<<<(ET + 255) / 256, 256, 0, stream>>>(ei, E, N, deg);
  scan_block_sums<<<P, 256, 0, stream>>>(deg, part, N);
  scan_partials<<<1, 256, 0, stream>>>(part, P);
  scan_final<<<P, 256, 0, stream>>>(deg, part, row_ptr, N);
  scatter_kernel<<<(ET + 255) / 256, 256, 0, stream>>>(ei, E, N, row_ptr, fill, col);

  const int NB4 = (N + 3) / 4;

  // ---- layer 1 ----
  gemm1_mfma<<<(N + 63) / 64, 256, 0, stream>>>(x, W1b, h1b, a_src1, a_dst1, as1, ad1, N);
  agg1_kernel<<<NB4, 256, 0, stream>>>(h1b, as1, ad1, row_ptr, col, b1, y1b, N);

  // ---- layer 2 ----
  gemm2_mfma<<<(N + 63) / 64, 256, 0, stream>>>(y1b, W2b, h2, a_src2, a_dst2, as2, ad2, N);
  agg2_kernel<<<NB4, 256, 0, stream>>>(h2, as2, ad2, row_ptr, col, b2, out, N);
}